// Round 12
// baseline (319.021 us; speedup 1.0000x reference)
//
#include <hip/hip_runtime.h>

// GumbelVQ — lane=code pass1 (async gumbel prefetch) + LDS-E pass2.
// Outputs (concatenated float32 in d_out):
//   [0 .. 8388607]      quantized  [16,16384,32]
//   [8388608]           commitment_loss (scalar)
//   [8388609 .. 8650752] indices   [16,16384] (stored as float)
//   [8650753]           perplexity (scalar)
//
// ws float layout:
//   [0..255]    avg_probs accumulator
//   [256]       loss accumulator
//   [257..512]  ||e_k||^2
//   [1024 .. 1024+M)  invS per row
//   floats from 1024+M : p (unnormalized numerators) bf16 [M][256]
//
// Round-12 vs round-11 (317us; pass1 207 VALU 55% Occ 40%, traffic at floor):
//  - pass1: gumbel tile tt+1 prefetched via global_load_lds issued AFTER the
//    post-phase-A barrier -> flies during phase B; drained by phase B's
//    barrier (compiler emits vmcnt(0) there). Removes the per-tile exposed
//    HBM latency of the synchronous stage. Zero VGPR/LDS cost.
//  - pass2: E staged in LDS (32 KB); per-code e-reads become uniform
//    broadcast ds_read_b128 (in-order, ~1-2cyc) instead of out-of-order
//    s_loads that force lgkmcnt(0) drains (r6 disease). Live regs ~60.

#define M_ROWS  262144
#define OUT_LOSS 8388608
#define OUT_IDX  8388609
#define OUT_PPL  8650753

#if defined(__has_builtin)
#if __has_builtin(__builtin_amdgcn_global_load_lds)
#define HAVE_GLLDS 1
#else
#define HAVE_GLLDS 0
#endif
#else
#define HAVE_GLLDS 0
#endif

typedef float f32x2 __attribute__((ext_vector_type(2)));

__device__ __forceinline__ f32x2 mk2(float a, float b) {
  f32x2 r; r.x = a; r.y = b; return r;
}

__device__ __forceinline__ unsigned int f2bf_u(float f) {
  unsigned int u = __float_as_uint(f);
  u += 0x7fffu + ((u >> 16) & 1u);
  return u >> 16;
}
__device__ __forceinline__ float bf2f(unsigned int lo16) {
  return __uint_as_float(lo16 << 16);
}

__global__ __launch_bounds__(256) void vq_prep(const float* __restrict__ emb,
                                               float* __restrict__ ws) {
  int t = threadIdx.x;
  ws[t] = 0.0f;                 // avg accumulators
  if (t == 0) ws[256] = 0.0f;   // loss accumulator
  const float4* e4 = (const float4*)emb;
  float s = 0.0f;
#pragma unroll
  for (int j = 0; j < 8; ++j) {
    float4 v = e4[t * 8 + j];
    s += v.x * v.x + v.y * v.y + v.z * v.z + v.w * v.w;
  }
  ws[257 + t] = s;
}

// ---- pass 1 (lane=code): logits, p(bf16), invS, argmax, loss ----------------
// 1024 blocks x 256 thr; block owns 256 rows in 16 tiles of 16.
__global__ __launch_bounds__(256, 4) void vq_pass1(
    const float* __restrict__ x_in, const float* __restrict__ emb,
    const float* __restrict__ gum, const float* __restrict__ ne,
    float* __restrict__ invS_ws, unsigned short* __restrict__ p_ws,
    float* __restrict__ loss_ws, float* __restrict__ out) {
  __shared__ __align__(16) float x_lds[16 * 36];    // 2304 B (16B-aligned rows)
  __shared__ __align__(16) float g_lds[16 * 256];   // 16384 B gumbel tile
  __shared__ float t_lds[256 * 17];                 // 17408 B [code][row]
  __shared__ float red_sum[16 * 17];                // 1088 B
  __shared__ float red_max[16 * 17];
  __shared__ int   red_idx[16 * 17];

  const int tid = threadIdx.x;
  const int wv  = tid >> 6;     // wave id 0..3 (wave-uniform)
  const int ln  = tid & 63;

  // embedding row for code=tid, resident in VGPRs (as 16 packed f32x2)
  f32x2 er2[16];
  {
    const float4* e4 = (const float4*)(emb + tid * 32);
#pragma unroll
    for (int j = 0; j < 8; ++j) {
      float4 v = e4[j];
      er2[2*j]   = mk2(v.x, v.y);
      er2[2*j+1] = mk2(v.z, v.w);
    }
  }
  const float ne_t = ne[tid];
  const int row_blk = blockIdx.x * 256;
  float cl_acc = 0.0f;

#if HAVE_GLLDS
  // async stage of a 16x256 f32 gumbel tile (linear layout == gum layout):
  // chunk i: lds bytes [i*4096 + wv*1024 .. +1024) <- gum tile + same offset.
  auto issue_g = [&](int ttn) {
    const char* gbase = (const char*)(gum + (size_t)(row_blk + ttn * 16) * 256);
#pragma unroll
    for (int i = 0; i < 4; ++i) {
      const int off = i * 4096 + wv * 1024;
      __builtin_amdgcn_global_load_lds(
          (const __attribute__((address_space(1))) void*)(gbase + off + ln * 16),
          (__attribute__((address_space(3))) void*)((char*)g_lds + off),
          16, 0, 0);
    }
  };
  issue_g(0);                               // prologue: tile 0 in flight
#endif

  for (int tt = 0; tt < 16; ++tt) {
    const int r0 = row_blk + tt * 16;

#if !HAVE_GLLDS
    // synchronous fallback: bulk-stage gumbel tile through VGPRs
    {
      const float4* gg = (const float4*)gum + (size_t)r0 * 64;
      float4* gd = (float4*)g_lds;
#pragma unroll
      for (int i = 0; i < 4; ++i) gd[i * 256 + tid] = gg[i * 256 + tid];
    }
#endif
    if (tid < 128)   // 16 rows of x (one float4 per thread)
      *((float4*)&x_lds[(tid >> 3) * 36 + (tid & 7) * 4]) =
          ((const float4*)x_in)[(size_t)r0 * 8 + tid];
    __syncthreads();   // drains vmcnt -> async g(tt) has landed; x visible

    // ---- phase A: logits for 16 rows x (code = tid), pk-fma dot ----
#pragma unroll 2
    for (int r = 0; r < 16; ++r) {
      const float4* xr4 = (const float4*)&x_lds[r * 36];
      f32x2 a0 = mk2(0.f, 0.f), a1 = mk2(0.f, 0.f);
#pragma unroll
      for (int j = 0; j < 8; ++j) {
        const float4 xv = xr4[j];                   // uniform broadcast read
        a0 = __builtin_elementwise_fma(mk2(xv.x, xv.y), er2[2*j],   a0);
        a1 = __builtin_elementwise_fma(mk2(xv.z, xv.w), er2[2*j+1], a1);
      }
      const float dot = (a0.x + a1.x) + (a0.y + a1.y);
      const float u = g_lds[r * 256 + tid];              // 2 lanes/bank: free
      const float g = -__logf(-__logf(u + 1e-20f) + 1e-20f);
      t_lds[tid * 17 + r] = fmaf(2.0f, dot, g) - ne_t;   // ||x||^2 row-const
    }
    __syncthreads();   // everyone done READING g_lds -> safe to overwrite

#if HAVE_GLLDS
    if (tt < 15) issue_g(tt + 1);   // flies during phase B; drained at next bar
#endif

    // ---- phase B: row = tid&15, codes (tid>>4)*16 .. +16 ----
    const int lrow = tid & 15;
    const int cs   = tid >> 4;
    {
      float ssum = 0.0f, tmax = -3.0e38f;
      int   kmax = 0;
      unsigned int packs[8];
#pragma unroll
      for (int j = 0; j < 16; ++j) {
        const int k = cs * 16 + j;
        const float tv = t_lds[k * 17 + lrow];
        const float p = __expf(tv);
        ssum += p;
        if (tv > tmax) { tmax = tv; kmax = k; }
        if (j & 1) packs[j >> 1] |= f2bf_u(p) << 16;   // static index
        else       packs[j >> 1]  = f2bf_u(p);
      }
      uint4* pout = (uint4*)(p_ws + (size_t)(r0 + lrow) * 256 + cs * 16);
      const uint4* pd = (const uint4*)packs;
      pout[0] = pd[0]; pout[1] = pd[1];          // 32B per thread, coalesced
      red_sum[lrow * 17 + cs] = ssum;
      red_max[lrow * 17 + cs] = tmax;
      red_idx[lrow * 17 + cs] = kmax;
    }
    __syncthreads();   // red visible; also drains the async g(tt+1) loads

    // ---- combine slices, write invS/idx, commitment loss (1 thr/row) ----
    if (tid < 16) {
      float ssum = 0.0f, tmax = -3.0e38f;
      int   kmax = 0;
#pragma unroll
      for (int c = 0; c < 16; ++c) {       // ascending c keeps first-index ties
        ssum += red_sum[tid * 17 + c];
        const float m = red_max[tid * 17 + c];
        if (m > tmax) { tmax = m; kmax = red_idx[tid * 17 + c]; }
      }
      const int rg = r0 + tid;
      invS_ws[rg] = 1.0f / ssum;
      out[OUT_IDX + rg] = (float)kmax;

      const float4* eh = (const float4*)(emb + (size_t)kmax * 32);  // L1-hot
      const float* xrr = &x_lds[tid * 36];
      float cl = 0.0f;
#pragma unroll
      for (int j = 0; j < 8; ++j) {
        const float4 e  = eh[j];
        const float4 xv = ((const float4*)xrr)[j];
        float dx;
        dx = e.x - xv.x; cl = fmaf(dx, dx, cl);
        dx = e.y - xv.y; cl = fmaf(dx, dx, cl);
        dx = e.z - xv.z; cl = fmaf(dx, dx, cl);
        dx = e.w - xv.w; cl = fmaf(dx, dx, cl);
      }
#pragma unroll
      for (int off = 8; off > 0; off >>= 1) cl += __shfl_down(cl, off, 16);
      if (tid == 0) cl_acc += cl;
    }
    __syncthreads();   // combine's x_lds reads done -> next tile may overwrite
  }
  if (tid == 0) atomicAdd(loss_ws, cl_acc);
}

// ---- pass 2 (LDS-E): quantized = tr*(p-hat @ E) + (1-tr)*e_hard -------------
__global__ __launch_bounds__(256, 4) void vq_pass2(
    const float* __restrict__ emb, const unsigned short* __restrict__ p_ws,
    const float* __restrict__ invS_ws, float* __restrict__ out) {
  __shared__ __align__(16) float e_lds[256 * 32];   // 32 KB

  const int tid = threadIdx.x;
  {
    const float4* src = (const float4*)emb;
    float4* dst = (float4*)e_lds;
#pragma unroll
    for (int j = 0; j < 8; ++j) dst[j * 256 + tid] = src[j * 256 + tid];
  }
  __syncthreads();

  const int row = blockIdx.x * 256 + tid;
  const float invS = invS_ws[row];
  const int imax = (int)out[OUT_IDX + row];
  const uint4* pv = (const uint4*)(p_ws + (size_t)row * 256);
  const float4* el4 = (const float4*)e_lds;

  f32x2 q2[16];
#pragma unroll
  for (int d = 0; d < 16; ++d) q2[d] = mk2(0.f, 0.f);

  for (int kg = 0; kg < 8; ++kg) {
    unsigned int w_[16];
#pragma unroll
    for (int j = 0; j < 4; ++j) {
      const uint4 v = pv[kg * 4 + j];
      w_[4*j+0] = v.x; w_[4*j+1] = v.y; w_[4*j+2] = v.z; w_[4*j+3] = v.w;
    }
#pragma unroll
    for (int i = 0; i < 16; ++i) {
      const int k0 = kg * 32 + 2 * i;
      const f32x2 pp0 = mk2(bf2f(w_[i] & 0xffffu), bf2f(w_[i] & 0xffffu));
      const f32x2 pp1 = mk2(bf2f(w_[i] >> 16),     bf2f(w_[i] >> 16));
#pragma unroll
      for (int jj = 0; jj < 8; ++jj) {
        const float4 e0 = el4[k0 * 8 + jj];       // uniform LDS broadcast
        const float4 e1 = el4[(k0 + 1) * 8 + jj];
        q2[2*jj]   = __builtin_elementwise_fma(mk2(e0.x, e0.y), pp0, q2[2*jj]);
        q2[2*jj+1] = __builtin_elementwise_fma(mk2(e0.z, e0.w), pp0, q2[2*jj+1]);
        q2[2*jj]   = __builtin_elementwise_fma(mk2(e1.x, e1.y), pp1, q2[2*jj]);
        q2[2*jj+1] = __builtin_elementwise_fma(mk2(e1.z, e1.w), pp1, q2[2*jj+1]);
      }
    }
  }

  const float tr  = 1.0f / 3.0f;     // (1.0-0.5)/(2.0-0.5)
  const float otr = 1.0f - tr;
  const float4* ehv = el4 + imax * 8;             // per-lane LDS gather
  float4* outq = (float4*)(out + (size_t)row * 32);
#pragma unroll
  for (int j = 0; j < 8; ++j) {
    float4 e = ehv[j];
    float4 o;
    o.x = fmaf(tr, q2[2*j].x   * invS, otr * e.x);
    o.y = fmaf(tr, q2[2*j].y   * invS, otr * e.y);
    o.z = fmaf(tr, q2[2*j+1].x * invS, otr * e.z);
    o.w = fmaf(tr, q2[2*j+1].y * invS, otr * e.w);
    outq[j] = o;
  }
}

// ---- avg_probs column sums (coalesced, 8192 waves) --------------------------
__global__ __launch_bounds__(256) void vq_avg(
    const unsigned short* __restrict__ p_ws, const float* __restrict__ invS_ws,
    float* __restrict__ avg_ws) {
  __shared__ float sh[256];
  const int tid = threadIdx.x, lane = tid & 63, w = tid >> 6;
  sh[tid] = 0.0f;
  __syncthreads();
  const int base = (blockIdx.x * 4 + w) * 32;   // 8192 waves, 32 rows each
  const float iv = invS_ws[base + (lane & 31)];
  float a0 = 0.f, a1 = 0.f, a2 = 0.f, a3 = 0.f;
#pragma unroll 4
  for (int r = 0; r < 32; ++r) {
    const float s = __shfl(iv, r);
    const unsigned short* pr = p_ws + (size_t)(base + r) * 256;
    a0 = fmaf(bf2f(pr[  0 + lane]), s, a0);
    a1 = fmaf(bf2f(pr[ 64 + lane]), s, a1);
    a2 = fmaf(bf2f(pr[128 + lane]), s, a2);
    a3 = fmaf(bf2f(pr[192 + lane]), s, a3);
  }
  atomicAdd(&sh[  0 + lane], a0);
  atomicAdd(&sh[ 64 + lane], a1);
  atomicAdd(&sh[128 + lane], a2);
  atomicAdd(&sh[192 + lane], a3);
  __syncthreads();
  atomicAdd(&avg_ws[tid], sh[tid]);
}

__global__ __launch_bounds__(256) void vq_fin(const float* __restrict__ ws,
                                              float* __restrict__ out) {
  __shared__ float red[256];
  int t = threadIdx.x;
  float avg = ws[t] * (1.0f / 262144.0f);
  red[t] = -avg * __logf(avg + 1e-10f);
  __syncthreads();
  for (int s = 128; s > 0; s >>= 1) {
    if (t < s) red[t] += red[t + s];
    __syncthreads();
  }
  if (t == 0) {
    out[OUT_PPL]  = __expf(red[0]);
    out[OUT_LOSS] = ws[256] * (1.0f / 8388608.0f);
  }
}

// ---- fallback (round-1 monolithic, if ws too small) -------------------------
__global__ __launch_bounds__(256, 1) void vq_main(
    const float* __restrict__ x_in, const float* __restrict__ emb,
    const float* __restrict__ gum, const float* __restrict__ ne,
    float* __restrict__ avg_ws, float* __restrict__ loss_ws,
    float* __restrict__ out) {
  extern __shared__ unsigned char dynsmem[];
  unsigned short* p_lds = (unsigned short*)dynsmem;

  const int tid  = threadIdx.x;
  const int lane = tid & 63;
  const int w    = tid >> 6;
  const int row  = blockIdx.x * 256 + tid;
  unsigned short* my_p = p_lds + (size_t)(w * 64 + lane) * 258;

  float xr[32];
  {
    const float4* xv = (const float4*)(x_in + (size_t)row * 32);
#pragma unroll
    for (int j = 0; j < 8; ++j) {
      float4 v = xv[j];
      xr[4*j+0] = v.x; xr[4*j+1] = v.y; xr[4*j+2] = v.z; xr[4*j+3] = v.w;
    }
  }
  float q[32];
#pragma unroll
  for (int d = 0; d < 32; ++d) q[d] = 0.0f;

  float ssum = 0.0f;
  float tmax = -3.0e38f;
  int   imax = 0;

  const float4* g4 = (const float4*)(gum + (size_t)row * 256);
  const float4* e4 = (const float4*)emb;

  for (int kg = 0; kg < 8; ++kg) {
    float uv[32];
#pragma unroll
    for (int j = 0; j < 8; ++j) {
      float4 v = g4[kg * 8 + j];
      uv[4*j+0] = v.x; uv[4*j+1] = v.y; uv[4*j+2] = v.z; uv[4*j+3] = v.w;
    }
#pragma unroll
    for (int kk = 0; kk < 32; ++kk) {
      const int k = kg * 32 + kk;
      float er[32];
#pragma unroll
      for (int j = 0; j < 8; ++j) {
        float4 v = e4[k * 8 + j];
        er[4*j+0] = v.x; er[4*j+1] = v.y; er[4*j+2] = v.z; er[4*j+3] = v.w;
      }
      float d0 = 0.f, d1 = 0.f, d2 = 0.f, d3 = 0.f;
#pragma unroll
      for (int d = 0; d < 32; d += 4) {
        d0 = fmaf(xr[d+0], er[d+0], d0);
        d1 = fmaf(xr[d+1], er[d+1], d1);
        d2 = fmaf(xr[d+2], er[d+2], d2);
        d3 = fmaf(xr[d+3], er[d+3], d3);
      }
      const float dot = (d0 + d1) + (d2 + d3);
      const float inner = -__logf(uv[kk] + 1e-20f);
      const float g = -__logf(inner + 1e-20f);
      const float t = fmaf(2.0f, dot, g) - ne[k];
      const float p = __expf(t);
      ssum += p;
      if (t > tmax) { tmax = t; imax = k; }
#pragma unroll
      for (int d = 0; d < 32; ++d) q[d] = fmaf(p, er[d], q[d]);
      my_p[k] = (unsigned short)f2bf_u(p);
    }
  }

  const float invS = 1.0f / ssum;
  {
    const float tr  = 1.0f / 3.0f;
    const float otr = 1.0f - tr;
    const float4* ehv = (const float4*)(emb + (size_t)imax * 32);
    float4* outq = (float4*)(out + (size_t)row * 32);
    float cl = 0.0f;
#pragma unroll
    for (int j = 0; j < 8; ++j) {
      float4 e = ehv[j];
      float4 o;
      float qs, dx;
      qs = q[4*j+0]*invS; o.x = tr*qs + otr*e.x; dx = e.x - xr[4*j+0]; cl = fmaf(dx,dx,cl);
      qs = q[4*j+1]*invS; o.y = tr*qs + otr*e.y; dx = e.y - xr[4*j+1]; cl = fmaf(dx,dx,cl);
      qs = q[4*j+2]*invS; o.z = tr*qs + otr*e.z; dx = e.z - xr[4*j+2]; cl = fmaf(dx,dx,cl);
      qs = q[4*j+3]*invS; o.w = tr*qs + otr*e.w; dx = e.w - xr[4*j+3]; cl = fmaf(dx,dx,cl);
      outq[j] = o;
    }
    out[OUT_IDX + row] = (float)imax;
#pragma unroll
    for (int off = 32; off > 0; off >>= 1) cl += __shfl_down(cl, off);
    if (lane == 0) atomicAdd(loss_ws, cl);
  }

  __syncthreads();

  float a0 = 0.f, a1 = 0.f, a2 = 0.f, a3 = 0.f;
  for (int r = 0; r < 64; ++r) {
    const float invS_r = __shfl(invS, r);
    const unsigned short* rp = p_lds + (size_t)(w * 64 + r) * 258;
    a0 = fmaf(bf2f(rp[  0 + lane]), invS_r, a0);
    a1 = fmaf(bf2f(rp[ 64 + lane]), invS_r, a1);
    a2 = fmaf(bf2f(rp[128 + lane]), invS_r, a2);
    a3 = fmaf(bf2f(rp[192 + lane]), invS_r, a3);
  }
  atomicAdd(&avg_ws[  0 + lane], a0);
  atomicAdd(&avg_ws[ 64 + lane], a1);
  atomicAdd(&avg_ws[128 + lane], a2);
  atomicAdd(&avg_ws[192 + lane], a3);
}

extern "C" void kernel_launch(void* const* d_in, const int* in_sizes, int n_in,
                              void* d_out, int out_size, void* d_ws, size_t ws_size,
                              hipStream_t stream) {
  const float* x   = (const float*)d_in[0];
  const float* emb = (const float*)d_in[1];
  const float* gum = (const float*)d_in[2];
  float* out = (float*)d_out;
  float* ws  = (float*)d_ws;

  (void)in_sizes; (void)n_in; (void)out_size;

  vq_prep<<<1, 256, 0, stream>>>(emb, ws);

  const size_t need = (size_t)(1024 + M_ROWS) * 4 + (size_t)M_ROWS * 256 * 2;
  if (ws_size >= need) {
    float* invS = ws + 1024;
    unsigned short* p = (unsigned short*)(ws + 1024 + M_ROWS);
    vq_pass1<<<1024, 256, 0, stream>>>(x, emb, gum, ws + 257, invS, p, ws + 256, out);
    vq_pass2<<<1024, 256, 0, stream>>>(emb, p, invS, out);
    vq_avg<<<2048, 256, 0, stream>>>(p, invS, ws);
  } else {
    hipFuncSetAttribute((const void*)vq_main,
                        hipFuncAttributeMaxDynamicSharedMemorySize, 132128);
    vq_main<<<1024, 256, 132128, stream>>>(x, emb, gum, ws + 257, ws, ws + 256, out);
  }
  vq_fin<<<1, 256, 0, stream>>>(ws, out);
}

// Round 14
// 262.327 us; speedup vs baseline: 1.2161x; 1.2161x over previous
//
#include <hip/hip_runtime.h>

// GumbelVQ — lane=code pass1 (log2-domain softmax) + LDS-E pass2 + u32 avg.
// Outputs (concatenated float32 in d_out):
//   [0 .. 8388607]      quantized  [16,16384,32]
//   [8388608]           commitment_loss (scalar)
//   [8388609 .. 8650752] indices   [16,16384] (stored as float)
//   [8650753]           perplexity (scalar)
//
// ws float layout:
//   [0..255]    avg_probs accumulator
//   [256]       loss accumulator
//   [257..512]  ||e_k||^2   (used only by fallback)
//   [1024 .. 1024+M)  invS per row
//   floats from 1024+M : p (unnormalized numerators, exp2 domain) bf16 [M][256]
//
// Round-14 = round-13 with the compile fix: HIP has no __exp2f intrinsic
// (glibc macro collision); exp2f() lowers to v_exp_f32 (natively 2^x).
// Design (vs r12, 319us; pass1 205us = ~115us VALU issue at 12.8 waves/CU):
//  - log2-domain: er2 pre-scaled by 2*log2e at load (free); gumbel term
//    g' = GOFF - log2(EPS2 - log2(u+1e-20)); p = exp2(t'). Removes the
//    ln2/log2e fixup mults of __logf/__expf. Monotone -> argmax preserved.
//  - ne computed from resident er2 (drops the ne global load).
//  - phase A '#pragma unroll 1': fewer live temps -> lower VGPR -> more waves.
//  - vq_avg: one uint2 (8B) load per row per lane instead of 4x2B.

#define M_ROWS  262144
#define OUT_LOSS 8388608
#define OUT_IDX  8388609
#define OUT_PPL  8650753

#if defined(__has_builtin)
#if __has_builtin(__builtin_amdgcn_global_load_lds)
#define HAVE_GLLDS 1
#else
#define HAVE_GLLDS 0
#endif
#else
#define HAVE_GLLDS 0
#endif

typedef float f32x2 __attribute__((ext_vector_type(2)));

__device__ __forceinline__ f32x2 mk2(float a, float b) {
  f32x2 r; r.x = a; r.y = b; return r;
}

__device__ __forceinline__ unsigned int f2bf_u(float f) {
  unsigned int u = __float_as_uint(f);
  u += 0x7fffu + ((u >> 16) & 1u);
  return u >> 16;
}
__device__ __forceinline__ float bf2f(unsigned int lo16) {
  return __uint_as_float(lo16 << 16);
}

__global__ __launch_bounds__(256) void vq_prep(const float* __restrict__ emb,
                                               float* __restrict__ ws) {
  int t = threadIdx.x;
  ws[t] = 0.0f;                 // avg accumulators
  if (t == 0) ws[256] = 0.0f;   // loss accumulator
  const float4* e4 = (const float4*)emb;
  float s = 0.0f;
#pragma unroll
  for (int j = 0; j < 8; ++j) {
    float4 v = e4[t * 8 + j];
    s += v.x * v.x + v.y * v.y + v.z * v.z + v.w * v.w;
  }
  ws[257 + t] = s;              // fallback path only
}

// ---- pass 1 (lane=code, log2 domain): logits, p(bf16), invS, argmax, loss ---
// 1024 blocks x 256 thr; block owns 256 rows in 16 tiles of 16.
__global__ __launch_bounds__(256, 4) void vq_pass1(
    const float* __restrict__ x_in, const float* __restrict__ emb,
    const float* __restrict__ gum,
    float* __restrict__ invS_ws, unsigned short* __restrict__ p_ws,
    float* __restrict__ loss_ws, float* __restrict__ out) {
  __shared__ __align__(16) float x_lds[16 * 36];    // 2304 B (16B-aligned rows)
  __shared__ __align__(16) float g_lds[16 * 256];   // 16384 B gumbel tile
  __shared__ float t_lds[256 * 17];                 // 17408 B [code][row]
  __shared__ float red_sum[16 * 17];                // 1088 B
  __shared__ float red_max[16 * 17];
  __shared__ int   red_idx[16 * 17];

  const int tid = threadIdx.x;
  const int wv  = tid >> 6;     // wave id 0..3 (wave-uniform)
  const int ln  = tid & 63;

  const float S2    = 2.8853900817779268f;   // 2*log2(e)
  const float L2E   = 1.4426950408889634f;   // log2(e)
  const float GOFF  = 0.5287663729448977f;   // -log2(ln2)
  const float EPS2  = 1.4426950408889634e-20f;

  // embedding row for code=tid, pre-scaled by 2*log2e; ne from same data
  f32x2 er2[16];
  float ne_t;
  {
    const float4* e4 = (const float4*)(emb + tid * 32);
    float na = 0.0f;
#pragma unroll
    for (int j = 0; j < 8; ++j) {
      float4 v = e4[j];
      na = fmaf(v.x, v.x, na); na = fmaf(v.y, v.y, na);
      na = fmaf(v.z, v.z, na); na = fmaf(v.w, v.w, na);
      er2[2*j]   = mk2(v.x * S2, v.y * S2);
      er2[2*j+1] = mk2(v.z * S2, v.w * S2);
    }
    ne_t = na * L2E;            // log2-domain ||e||^2 term
  }
  const int row_blk = blockIdx.x * 256;
  float cl_acc = 0.0f;

#if HAVE_GLLDS
  auto issue_g = [&](int ttn) {
    const char* gbase = (const char*)(gum + (size_t)(row_blk + ttn * 16) * 256);
#pragma unroll
    for (int i = 0; i < 4; ++i) {
      const int off = i * 4096 + wv * 1024;
      __builtin_amdgcn_global_load_lds(
          (const __attribute__((address_space(1))) void*)(gbase + off + ln * 16),
          (__attribute__((address_space(3))) void*)((char*)g_lds + off),
          16, 0, 0);
    }
  };
  issue_g(0);                               // prologue: tile 0 in flight
#endif

  for (int tt = 0; tt < 16; ++tt) {
    const int r0 = row_blk + tt * 16;

#if !HAVE_GLLDS
    {
      const float4* gg = (const float4*)gum + (size_t)r0 * 64;
      float4* gd = (float4*)g_lds;
#pragma unroll
      for (int i = 0; i < 4; ++i) gd[i * 256 + tid] = gg[i * 256 + tid];
    }
#endif
    if (tid < 128)   // 16 rows of x (one float4 per thread)
      *((float4*)&x_lds[(tid >> 3) * 36 + (tid & 7) * 4]) =
          ((const float4*)x_in)[(size_t)r0 * 8 + tid];
    __syncthreads();   // drains vmcnt -> async g(tt) landed; x visible

    // ---- phase A: log2-domain logits for 16 rows x (code = tid) ----
#pragma unroll 1
    for (int r = 0; r < 16; ++r) {
      const float u = g_lds[r * 256 + tid];            // 2 lanes/bank: free
      // g' = GOFF - log2(EPS2 - log2(u+1e-20))
      const float L1 = __log2f(u + 1e-20f);            // negative
      const float gp = GOFF - __log2f(EPS2 - L1);
      const float4* xr4 = (const float4*)&x_lds[r * 36];
      f32x2 a0 = mk2(0.f, 0.f), a1 = mk2(0.f, 0.f);
#pragma unroll
      for (int j = 0; j < 8; ++j) {
        const float4 xv = xr4[j];                      // uniform broadcast
        a0 = __builtin_elementwise_fma(mk2(xv.x, xv.y), er2[2*j],   a0);
        a1 = __builtin_elementwise_fma(mk2(xv.z, xv.w), er2[2*j+1], a1);
      }
      const float dot2 = (a0.x + a1.x) + (a0.y + a1.y);  // = 2*log2e*(x.e)
      t_lds[tid * 17 + r] = dot2 + (gp - ne_t);
    }
    __syncthreads();   // g_lds consumed -> safe to overwrite

#if HAVE_GLLDS
    if (tt < 15) issue_g(tt + 1);   // flies during phase B
#endif

    // ---- phase B: row = tid&15, codes (tid>>4)*16 .. +16 ----
    const int lrow = tid & 15;
    const int cs   = tid >> 4;
    {
      float ssum = 0.0f, tmax = -3.0e38f;
      int   kmax = 0;
      unsigned int packs[8];
#pragma unroll
      for (int j = 0; j < 16; ++j) {
        const int k = cs * 16 + j;
        const float tv = t_lds[k * 17 + lrow];
        const float p = exp2f(tv);                     // v_exp_f32 (2^x native)
        ssum += p;
        if (tv > tmax) { tmax = tv; kmax = k; }
        if (j & 1) packs[j >> 1] |= f2bf_u(p) << 16;   // static index
        else       packs[j >> 1]  = f2bf_u(p);
      }
      uint4* pout = (uint4*)(p_ws + (size_t)(r0 + lrow) * 256 + cs * 16);
      const uint4* pd = (const uint4*)packs;
      pout[0] = pd[0]; pout[1] = pd[1];          // 32B per thread, coalesced
      red_sum[lrow * 17 + cs] = ssum;
      red_max[lrow * 17 + cs] = tmax;
      red_idx[lrow * 17 + cs] = kmax;
    }
    __syncthreads();   // red visible; drains async g(tt+1)

    // ---- combine slices, write invS/idx, commitment loss (1 thr/row) ----
    if (tid < 16) {
      float ssum = 0.0f, tmax = -3.0e38f;
      int   kmax = 0;
#pragma unroll
      for (int c = 0; c < 16; ++c) {       // ascending c keeps first-index ties
        ssum += red_sum[tid * 17 + c];
        const float m = red_max[tid * 17 + c];
        if (m > tmax) { tmax = m; kmax = red_idx[tid * 17 + c]; }
      }
      const int rg = r0 + tid;
      invS_ws[rg] = 1.0f / ssum;
      out[OUT_IDX + rg] = (float)kmax;

      const float4* eh = (const float4*)(emb + (size_t)kmax * 32);  // L1-hot
      const float* xrr = &x_lds[tid * 36];
      float cl = 0.0f;
#pragma unroll
      for (int j = 0; j < 8; ++j) {
        const float4 e  = eh[j];
        const float4 xv = ((const float4*)xrr)[j];
        float dx;
        dx = e.x - xv.x; cl = fmaf(dx, dx, cl);
        dx = e.y - xv.y; cl = fmaf(dx, dx, cl);
        dx = e.z - xv.z; cl = fmaf(dx, dx, cl);
        dx = e.w - xv.w; cl = fmaf(dx, dx, cl);
      }
#pragma unroll
      for (int off = 8; off > 0; off >>= 1) cl += __shfl_down(cl, off, 16);
      if (tid == 0) cl_acc += cl;
    }
    __syncthreads();   // x_lds reads done -> next tile may overwrite
  }
  if (tid == 0) atomicAdd(loss_ws, cl_acc);
}

// ---- pass 2 (LDS-E): quantized = tr*(p-hat @ E) + (1-tr)*e_hard -------------
__global__ __launch_bounds__(256, 4) void vq_pass2(
    const float* __restrict__ emb, const unsigned short* __restrict__ p_ws,
    const float* __restrict__ invS_ws, float* __restrict__ out) {
  __shared__ __align__(16) float e_lds[256 * 32];   // 32 KB

  const int tid = threadIdx.x;
  {
    const float4* src = (const float4*)emb;
    float4* dst = (float4*)e_lds;
#pragma unroll
    for (int j = 0; j < 8; ++j) dst[j * 256 + tid] = src[j * 256 + tid];
  }
  __syncthreads();

  const int row = blockIdx.x * 256 + tid;
  const float invS = invS_ws[row];
  const int imax = (int)out[OUT_IDX + row];
  const uint4* pv = (const uint4*)(p_ws + (size_t)row * 256);
  const float4* el4 = (const float4*)e_lds;

  f32x2 q2[16];
#pragma unroll
  for (int d = 0; d < 16; ++d) q2[d] = mk2(0.f, 0.f);

  for (int kg = 0; kg < 8; ++kg) {
    unsigned int w_[16];
#pragma unroll
    for (int j = 0; j < 4; ++j) {
      const uint4 v = pv[kg * 4 + j];
      w_[4*j+0] = v.x; w_[4*j+1] = v.y; w_[4*j+2] = v.z; w_[4*j+3] = v.w;
    }
#pragma unroll
    for (int i = 0; i < 16; ++i) {
      const int k0 = kg * 32 + 2 * i;
      const f32x2 pp0 = mk2(bf2f(w_[i] & 0xffffu), bf2f(w_[i] & 0xffffu));
      const f32x2 pp1 = mk2(bf2f(w_[i] >> 16),     bf2f(w_[i] >> 16));
#pragma unroll
      for (int jj = 0; jj < 8; ++jj) {
        const float4 e0 = el4[k0 * 8 + jj];       // uniform LDS broadcast
        const float4 e1 = el4[(k0 + 1) * 8 + jj];
        q2[2*jj]   = __builtin_elementwise_fma(mk2(e0.x, e0.y), pp0, q2[2*jj]);
        q2[2*jj+1] = __builtin_elementwise_fma(mk2(e0.z, e0.w), pp0, q2[2*jj+1]);
        q2[2*jj]   = __builtin_elementwise_fma(mk2(e1.x, e1.y), pp1, q2[2*jj]);
        q2[2*jj+1] = __builtin_elementwise_fma(mk2(e1.z, e1.w), pp1, q2[2*jj+1]);
      }
    }
  }

  const float tr  = 1.0f / 3.0f;     // (1.0-0.5)/(2.0-0.5)
  const float otr = 1.0f - tr;
  const float4* ehv = el4 + imax * 8;             // per-lane LDS gather
  float4* outq = (float4*)(out + (size_t)row * 32);
#pragma unroll
  for (int j = 0; j < 8; ++j) {
    float4 e = ehv[j];
    float4 o;
    o.x = fmaf(tr, q2[2*j].x   * invS, otr * e.x);
    o.y = fmaf(tr, q2[2*j].y   * invS, otr * e.y);
    o.z = fmaf(tr, q2[2*j+1].x * invS, otr * e.z);
    o.w = fmaf(tr, q2[2*j+1].y * invS, otr * e.w);
    outq[j] = o;
  }
}

// ---- avg_probs column sums (uint2 loads, 4096 waves) ------------------------
__global__ __launch_bounds__(256) void vq_avg(
    const unsigned short* __restrict__ p_ws, const float* __restrict__ invS_ws,
    float* __restrict__ avg_ws) {
  __shared__ float sh[256];
  const int tid = threadIdx.x, lane = tid & 63, w = tid >> 6;
  sh[tid] = 0.0f;
  __syncthreads();
  const int base = (blockIdx.x * 4 + w) * 64;   // 4096 waves, 64 rows each
  const float iv = invS_ws[base + lane];
  float a0 = 0.f, a1 = 0.f, a2 = 0.f, a3 = 0.f;
  for (int r = 0; r < 64; ++r) {
    const float s = __shfl(iv, r);
    // lane owns codes 4*lane..4*lane+3: one coalesced 8B load per row
    const uint2 u2 = ((const uint2*)(p_ws + (size_t)(base + r) * 256))[lane];
    a0 = fmaf(bf2f(u2.x & 0xffffu), s, a0);
    a1 = fmaf(bf2f(u2.x >> 16),     s, a1);
    a2 = fmaf(bf2f(u2.y & 0xffffu), s, a2);
    a3 = fmaf(bf2f(u2.y >> 16),     s, a3);
  }
  atomicAdd(&sh[4*lane+0], a0);
  atomicAdd(&sh[4*lane+1], a1);
  atomicAdd(&sh[4*lane+2], a2);
  atomicAdd(&sh[4*lane+3], a3);
  __syncthreads();
  atomicAdd(&avg_ws[tid], sh[tid]);
}

__global__ __launch_bounds__(256) void vq_fin(const float* __restrict__ ws,
                                              float* __restrict__ out) {
  __shared__ float red[256];
  int t = threadIdx.x;
  float avg = ws[t] * (1.0f / 262144.0f);
  red[t] = -avg * __logf(avg + 1e-10f);
  __syncthreads();
  for (int s = 128; s > 0; s >>= 1) {
    if (t < s) red[t] += red[t + s];
    __syncthreads();
  }
  if (t == 0) {
    out[OUT_PPL]  = __expf(red[0]);
    out[OUT_LOSS] = ws[256] * (1.0f / 8388608.0f);
  }
}

// ---- fallback (round-1 monolithic, if ws too small) -------------------------
__global__ __launch_bounds__(256, 1) void vq_main(
    const float* __restrict__ x_in, const float* __restrict__ emb,
    const float* __restrict__ gum, const float* __restrict__ ne,
    float* __restrict__ avg_ws, float* __restrict__ loss_ws,
    float* __restrict__ out) {
  extern __shared__ unsigned char dynsmem[];
  unsigned short* p_lds = (unsigned short*)dynsmem;

  const int tid  = threadIdx.x;
  const int lane = tid & 63;
  const int w    = tid >> 6;
  const int row  = blockIdx.x * 256 + tid;
  unsigned short* my_p = p_lds + (size_t)(w * 64 + lane) * 258;

  float xr[32];
  {
    const float4* xv = (const float4*)(x_in + (size_t)row * 32);
#pragma unroll
    for (int j = 0; j < 8; ++j) {
      float4 v = xv[j];
      xr[4*j+0] = v.x; xr[4*j+1] = v.y; xr[4*j+2] = v.z; xr[4*j+3] = v.w;
    }
  }
  float q[32];
#pragma unroll
  for (int d = 0; d < 32; ++d) q[d] = 0.0f;

  float ssum = 0.0f;
  float tmax = -3.0e38f;
  int   imax = 0;

  const float4* g4 = (const float4*)(gum + (size_t)row * 256);
  const float4* e4 = (const float4*)emb;

  for (int kg = 0; kg < 8; ++kg) {
    float uv[32];
#pragma unroll
    for (int j = 0; j < 8; ++j) {
      float4 v = g4[kg * 8 + j];
      uv[4*j+0] = v.x; uv[4*j+1] = v.y; uv[4*j+2] = v.z; uv[4*j+3] = v.w;
    }
#pragma unroll
    for (int kk = 0; kk < 32; ++kk) {
      const int k = kg * 32 + kk;
      float er[32];
#pragma unroll
      for (int j = 0; j < 8; ++j) {
        float4 v = e4[k * 8 + j];
        er[4*j+0] = v.x; er[4*j+1] = v.y; er[4*j+2] = v.z; er[4*j+3] = v.w;
      }
      float d0 = 0.f, d1 = 0.f, d2 = 0.f, d3 = 0.f;
#pragma unroll
      for (int d = 0; d < 32; d += 4) {
        d0 = fmaf(xr[d+0], er[d+0], d0);
        d1 = fmaf(xr[d+1], er[d+1], d1);
        d2 = fmaf(xr[d+2], er[d+2], d2);
        d3 = fmaf(xr[d+3], er[d+3], d3);
      }
      const float dot = (d0 + d1) + (d2 + d3);
      const float inner = -__logf(uv[kk] + 1e-20f);
      const float g = -__logf(inner + 1e-20f);
      const float t = fmaf(2.0f, dot, g) - ne[k];
      const float p = __expf(t);
      ssum += p;
      if (t > tmax) { tmax = t; imax = k; }
#pragma unroll
      for (int d = 0; d < 32; ++d) q[d] = fmaf(p, er[d], q[d]);
      my_p[k] = (unsigned short)f2bf_u(p);
    }
  }

  const float invS = 1.0f / ssum;
  {
    const float tr  = 1.0f / 3.0f;
    const float otr = 1.0f - tr;
    const float4* ehv = (const float4*)(emb + (size_t)imax * 32);
    float4* outq = (float4*)(out + (size_t)row * 32);
    float cl = 0.0f;
#pragma unroll
    for (int j = 0; j < 8; ++j) {
      float4 e = ehv[j];
      float4 o;
      float qs, dx;
      qs = q[4*j+0]*invS; o.x = tr*qs + otr*e.x; dx = e.x - xr[4*j+0]; cl = fmaf(dx,dx,cl);
      qs = q[4*j+1]*invS; o.y = tr*qs + otr*e.y; dx = e.y - xr[4*j+1]; cl = fmaf(dx,dx,cl);
      qs = q[4*j+2]*invS; o.z = tr*qs + otr*e.z; dx = e.z - xr[4*j+2]; cl = fmaf(dx,dx,cl);
      qs = q[4*j+3]*invS; o.w = tr*qs + otr*e.w; dx = e.w - xr[4*j+3]; cl = fmaf(dx,dx,cl);
      outq[j] = o;
    }
    out[OUT_IDX + row] = (float)imax;
#pragma unroll
    for (int off = 32; off > 0; off >>= 1) cl += __shfl_down(cl, off);
    if (lane == 0) atomicAdd(loss_ws, cl);
  }

  __syncthreads();

  float a0 = 0.f, a1 = 0.f, a2 = 0.f, a3 = 0.f;
  for (int r = 0; r < 64; ++r) {
    const float invS_r = __shfl(invS, r);
    const unsigned short* rp = p_lds + (size_t)(w * 64 + r) * 258;
    a0 = fmaf(bf2f(rp[  0 + lane]), invS_r, a0);
    a1 = fmaf(bf2f(rp[ 64 + lane]), invS_r, a1);
    a2 = fmaf(bf2f(rp[128 + lane]), invS_r, a2);
    a3 = fmaf(bf2f(rp[192 + lane]), invS_r, a3);
  }
  atomicAdd(&avg_ws[  0 + lane], a0);
  atomicAdd(&avg_ws[ 64 + lane], a1);
  atomicAdd(&avg_ws[128 + lane], a2);
  atomicAdd(&avg_ws[192 + lane], a3);
}

extern "C" void kernel_launch(void* const* d_in, const int* in_sizes, int n_in,
                              void* d_out, int out_size, void* d_ws, size_t ws_size,
                              hipStream_t stream) {
  const float* x   = (const float*)d_in[0];
  const float* emb = (const float*)d_in[1];
  const float* gum = (const float*)d_in[2];
  float* out = (float*)d_out;
  float* ws  = (float*)d_ws;

  (void)in_sizes; (void)n_in; (void)out_size;

  vq_prep<<<1, 256, 0, stream>>>(emb, ws);

  const size_t need = (size_t)(1024 + M_ROWS) * 4 + (size_t)M_ROWS * 256 * 2;
  if (ws_size >= need) {
    float* invS = ws + 1024;
    unsigned short* p = (unsigned short*)(ws + 1024 + M_ROWS);
    vq_pass1<<<1024, 256, 0, stream>>>(x, emb, gum, invS, p, ws + 256, out);
    vq_pass2<<<1024, 256, 0, stream>>>(emb, p, invS, out);
    vq_avg<<<1024, 256, 0, stream>>>(p, invS, ws);
  } else {
    (void)hipFuncSetAttribute((const void*)vq_main,
                        hipFuncAttributeMaxDynamicSharedMemorySize, 132128);
    vq_main<<<1024, 256, 132128, stream>>>(x, emb, gum, ws + 257, ws, ws + 256, out);
  }
  vq_fin<<<1, 256, 0, stream>>>(ws, out);
}